// Round 11
// baseline (426.438 us; speedup 1.0000x reference)
//
#include <hip/hip_runtime.h>
#include <hip/hip_bf16.h>
#include <math.h>

#define DIM 256
#define NHEAD 8
#define NTOK 10
#define LTOK 5120
#define EPS 1e-5f

typedef __attribute__((ext_vector_type(8))) short bh8;
typedef __attribute__((ext_vector_type(4))) short sh4;
typedef __attribute__((ext_vector_type(4))) float fx4;
typedef unsigned short LRow[DIM + 8];

__device__ inline unsigned short f2bf(float f) {
    unsigned int u = __builtin_bit_cast(unsigned int, f);
    u += 0x7fffu + ((u >> 16) & 1u);
    return (unsigned short)(u >> 16);
}
__device__ inline float bf2f(unsigned short h) {
    return __builtin_bit_cast(float, (unsigned int)h << 16);
}

// ---- kernel 0: weight prep. f32 [K][N] -> bf16 MFMA-fragment order:
//      wtf[((mat*4+s)*4+ni)*8+ko][lane][j] = W[ko*32+(lane>>4)*8+j][s*64+ni*16+(lane&15)]
__global__ void prep_kernel(const float* __restrict__ w1,
                            const float* __restrict__ w2,
                            unsigned short* __restrict__ wtf) {
    int gid = blockIdx.x * 256 + threadIdx.x;   // 16384 threads, 8 shorts each
    int lane = gid & 63;
    int ko = (gid >> 6) & 7;
    int ni = (gid >> 9) & 3;
    int s  = (gid >> 11) & 3;
    int mat = gid >> 13;
    const float* src = mat ? w2 : w1;
    int col = s * 64 + ni * 16 + (lane & 15);
    int k0 = ko * 32 + (lane >> 4) * 8;
    unsigned short* dst = wtf + (size_t)gid * 8;
    #pragma unroll
    for (int j = 0; j < 8; ++j)
        dst[j] = f2bf(src[(k0 + j) * 256 + col]);
}

// ---- fused kernel: block = (b, rh, half) -> 5 H-rows x 32 W-cols = 160 tokens.
//      Phase A: x -> bf16 LDS.  Phase B: 16 windows attention in-LDS (2/wave).
//      Phase C: LN2 + MLP (MFMA) + residual -> d_out, 5 chunks of 32 rows.
__global__ __launch_bounds__(512) void fused_kernel(
    const float* __restrict__ x, const float* __restrict__ g1,
    const float* __restrict__ b1, const float* __restrict__ btab,
    const float* __restrict__ g2, const float* __restrict__ b2,
    const unsigned short* __restrict__ wtf,
    const float* __restrict__ mb1, const float* __restrict__ mb2,
    float* __restrict__ out) {

    __shared__ unsigned short x1t[160][DIM + 8];        // 84480 B: x, then x+attn (bf16)
    __shared__ __align__(16) char scratch[33792];       // pmw (attn) / As2+h1t (mlp)
    __shared__ float biasT[216];                        // rel-bias table [27][8]

    float (*pmw)[800] = (float (*)[800])scratch;        // per-wave logits 8*10*10
    LRow* As2 = (LRow*)scratch;                         // [32][264] LN2'd bf16
    LRow* h1t = (LRow*)(scratch + sizeof(LRow) * 32);   // [32][264] gelu out bf16

    int tid = threadIdx.x;
    int lane = tid & 63;
    int w = tid >> 6;                                   // wave 0..7

    int blk = blockIdx.x;                               // b*32 + rh*2 + hf
    int b = blk >> 5;
    int rh = (blk >> 1) & 15;
    int hf = blk & 1;
    size_t tb = (size_t)b * LTOK + (size_t)(rh * 5) * 64 + hf * 32;

    // ---------------- phase A: stage x as bf16 ----------------
    if (tid < 216) biasT[tid] = btab[tid];
    #pragma unroll
    for (int it = 0; it < 20; ++it) {
        int t = tid + it * 512;
        int r = t >> 6;                                 // LDS row 0..159 (= i*32+j)
        int qd = t & 63;                                // float4 index in row
        const float4 v = *(const float4*)(x + (tb + (size_t)(r >> 5) * 64 + (r & 31)) * DIM + qd * 4);
        sh4 hh;
        hh.x = (short)f2bf(v.x); hh.y = (short)f2bf(v.y);
        hh.z = (short)f2bf(v.z); hh.w = (short)f2bf(v.w);
        *(sh4*)&x1t[r][qd * 4] = hh;
    }
    __syncthreads();

    // ---------------- phase B: window attention (2 windows / wave) ----------------
    {
        int hd = lane >> 3;                             // head 0..7 (ch = 4*lane)
        float g4x[4], b4x[4];
        {
            const float4 gg = *(const float4*)(g1 + lane * 4);
            const float4 bb = *(const float4*)(b1 + lane * 4);
            g4x[0] = gg.x; g4x[1] = gg.y; g4x[2] = gg.z; g4x[3] = gg.w;
            b4x[0] = bb.x; b4x[1] = bb.y; b4x[2] = bb.z; b4x[3] = bb.w;
        }
        float* pw = pmw[w];
        const float scale = 0.17677669529663689f;       // 32^-0.5

        for (int wd2 = 0; wd2 < 2; ++wd2) {
            int colb = (w * 2 + wd2) * 2;               // window's first col (0..30)

            // LN1 of the window's 10 tokens; hs in registers (4 ch/lane)
            float hs[NTOK][4];
            #pragma unroll
            for (int tk = 0; tk < NTOK; ++tk) {
                int rt = (tk >> 1) * 32 + colb + (tk & 1);
                sh4 xv = *(const sh4*)&x1t[rt][lane * 4];
                float f0 = bf2f((unsigned short)xv.x);
                float f1 = bf2f((unsigned short)xv.y);
                float f2 = bf2f((unsigned short)xv.z);
                float f3 = bf2f((unsigned short)xv.w);
                float s = f0 + f1 + f2 + f3;
                float sq = f0 * f0 + f1 * f1 + f2 * f2 + f3 * f3;
                #pragma unroll
                for (int off = 32; off > 0; off >>= 1) {
                    s += __shfl_xor(s, off);
                    sq += __shfl_xor(sq, off);
                }
                float mean = s * (1.0f / DIM);
                float rstd = rsqrtf(sq * (1.0f / DIM) - mean * mean + EPS);
                hs[tk][0] = (f0 - mean) * rstd * g4x[0] + b4x[0];
                hs[tk][1] = (f1 - mean) * rstd * g4x[1] + b4x[1];
                hs[tk][2] = (f2 - mean) * rstd * g4x[2] + b4x[2];
                hs[tk][3] = (f3 - mean) * rstd * g4x[3] + b4x[3];
            }

            // logits + rel bias -> pw[(hd*10+q)*10+k]
            #pragma unroll
            for (int q = 0; q < NTOK; ++q)
                #pragma unroll
                for (int k = 0; k < NTOK; ++k) {
                    float p = hs[q][0] * hs[k][0] + hs[q][1] * hs[k][1]
                            + hs[q][2] * hs[k][2] + hs[q][3] * hs[k][3];
                    p += __shfl_xor(p, 1);
                    p += __shfl_xor(p, 2);
                    p += __shfl_xor(p, 4);
                    int bidx = ((q >> 1) - (k >> 1) + 4) * 3 + ((q & 1) - (k & 1) + 1);
                    if ((lane & 7) == 0)
                        pw[(hd * NTOK + q) * NTOK + k] = p * scale + biasT[bidx * 8 + hd];
                }
            __syncthreads();

            // softmax: 80 rows of 10 (lane -> row, then rows 64..79 by lanes 0..15)
            {
                float* row = pw + lane * NTOK;
                float m = row[0];
                #pragma unroll
                for (int k = 1; k < NTOK; ++k) m = fmaxf(m, row[k]);
                float e[NTOK]; float s = 0.f;
                #pragma unroll
                for (int k = 0; k < NTOK; ++k) { e[k] = __expf(row[k] - m); s += e[k]; }
                float inv = 1.0f / s;
                #pragma unroll
                for (int k = 0; k < NTOK; ++k) row[k] = e[k] * inv;
            }
            if (lane < 16) {
                float* row = pw + (64 + lane) * NTOK;
                float m = row[0];
                #pragma unroll
                for (int k = 1; k < NTOK; ++k) m = fmaxf(m, row[k]);
                float e[NTOK]; float s = 0.f;
                #pragma unroll
                for (int k = 0; k < NTOK; ++k) { e[k] = __expf(row[k] - m); s += e[k]; }
                float inv = 1.0f / s;
                #pragma unroll
                for (int k = 0; k < NTOK; ++k) row[k] = e[k] * inv;
            }
            __syncthreads();

            // PV + residual, in-place into x1t (rows exclusive to this wave)
            #pragma unroll
            for (int q = 0; q < NTOK; ++q) {
                float a0 = 0.f, a1 = 0.f, a2 = 0.f, a3 = 0.f;
                #pragma unroll
                for (int k = 0; k < NTOK; ++k) {
                    float pv = pw[(hd * NTOK + q) * NTOK + k];
                    a0 += pv * hs[k][0]; a1 += pv * hs[k][1];
                    a2 += pv * hs[k][2]; a3 += pv * hs[k][3];
                }
                int rt = (q >> 1) * 32 + colb + (q & 1);
                sh4 xv = *(const sh4*)&x1t[rt][lane * 4];
                sh4 o;
                o.x = (short)f2bf(bf2f((unsigned short)xv.x) + a0);
                o.y = (short)f2bf(bf2f((unsigned short)xv.y) + a1);
                o.z = (short)f2bf(bf2f((unsigned short)xv.z) + a2);
                o.w = (short)f2bf(bf2f((unsigned short)xv.w) + a3);
                *(sh4*)&x1t[rt][lane * 4] = o;
            }
            __syncthreads();
        }
    }
    __syncthreads();

    // ---------------- phase C: LN2 + MLP + residual, 5 chunks of 32 rows ----------------
    int rr = tid >> 4;                                  // 0..31 (LN2 row)
    int qq = tid & 15;                                  // 16-ch segment
    float g2v[16], b2v[16];
    {
        const float4* gp = (const float4*)(g2 + qq * 16);
        const float4* bp = (const float4*)(b2 + qq * 16);
        #pragma unroll
        for (int u = 0; u < 4; ++u) {
            float4 gg = gp[u], bb = bp[u];
            g2v[u * 4] = gg.x; g2v[u * 4 + 1] = gg.y; g2v[u * 4 + 2] = gg.z; g2v[u * 4 + 3] = gg.w;
            b2v[u * 4] = bb.x; b2v[u * 4 + 1] = bb.y; b2v[u * 4 + 2] = bb.z; b2v[u * 4 + 3] = bb.w;
        }
    }
    int lr = lane & 15, lk = lane >> 4;
    int mt = w >> 2;                                    // row-tile 0..1 (16 rows)
    int ns = w & 3;                                     // 64-col strip 0..3
    const unsigned short* w1base = wtf + (size_t)ns * 16384 + (size_t)lane * 8;
    const unsigned short* w2base = w1base + 65536;
    float bias1v[4], bias2v[4];
    #pragma unroll
    for (int ni = 0; ni < 4; ++ni) {
        bias1v[ni] = mb1[ns * 64 + ni * 16 + lr];
        bias2v[ni] = mb2[ns * 64 + ni * 16 + lr];
    }
    const fx4 zero = {0.f, 0.f, 0.f, 0.f};

    for (int c = 0; c < 5; ++c) {
        // C1: LN2 of 32 rows -> As2 (bf16)
        {
            bh8 v0 = *(const bh8*)&x1t[c * 32 + rr][qq * 16];
            bh8 v1 = *(const bh8*)&x1t[c * 32 + rr][qq * 16 + 8];
            float f[16];
            #pragma unroll
            for (int e = 0; e < 8; ++e) {
                f[e] = bf2f((unsigned short)v0[e]);
                f[8 + e] = bf2f((unsigned short)v1[e]);
            }
            float sm = 0.f, sq = 0.f;
            #pragma unroll
            for (int e = 0; e < 16; ++e) { sm += f[e]; sq += f[e] * f[e]; }
            sm += __shfl_xor(sm, 1); sm += __shfl_xor(sm, 2); sm += __shfl_xor(sm, 4); sm += __shfl_xor(sm, 8);
            sq += __shfl_xor(sq, 1); sq += __shfl_xor(sq, 2); sq += __shfl_xor(sq, 4); sq += __shfl_xor(sq, 8);
            float mean = sm * (1.0f / DIM);
            float rstd = rsqrtf(sq * (1.0f / DIM) - mean * mean + EPS);
            bh8 h0, h1v;
            #pragma unroll
            for (int e = 0; e < 8; ++e) {
                h0[e] = (short)f2bf((f[e] - mean) * rstd * g2v[e] + b2v[e]);
                h1v[e] = (short)f2bf((f[8 + e] - mean) * rstd * g2v[8 + e] + b2v[8 + e]);
            }
            *(bh8*)&As2[rr][qq * 16] = h0;
            *(bh8*)&As2[rr][qq * 16 + 8] = h1v;
        }
        __syncthreads();

        // C2: GEMM1 — wave tile = rows mt*16..+15, cols ns*64..+63
        fx4 acc[4];
        #pragma unroll
        for (int ni = 0; ni < 4; ++ni) acc[ni] = zero;
        #pragma unroll
        for (int ko = 0; ko < 8; ++ko) {
            bh8 wfv[4];
            #pragma unroll
            for (int ni = 0; ni < 4; ++ni)
                wfv[ni] = *(const bh8*)(w1base + (size_t)(ni * 8 + ko) * 512);
            bh8 a = *(const bh8*)&As2[mt * 16 + lr][ko * 32 + lk * 8];
            #pragma unroll
            for (int ni = 0; ni < 4; ++ni)
                acc[ni] = __builtin_amdgcn_mfma_f32_16x16x32_bf16(a, wfv[ni], acc[ni], 0, 0, 0);
        }

        // C3: bias1 + gelu -> h1t (wave-local write)
        #pragma unroll
        for (int ni = 0; ni < 4; ++ni)
            #pragma unroll
            for (int r4 = 0; r4 < 4; ++r4) {
                float vv = acc[ni][r4] + bias1v[ni];
                float t2 = 0.7978845608028654f * (vv + 0.044715f * vv * vv * vv);
                float ge = vv / (1.0f + __expf(-2.0f * t2));
                h1t[mt * 16 + lk * 4 + r4][ns * 64 + ni * 16 + lr] = f2bf(ge);
            }
        __syncthreads();

        // C4: GEMM2
        fx4 acc2[4];
        #pragma unroll
        for (int ni = 0; ni < 4; ++ni) acc2[ni] = zero;
        #pragma unroll
        for (int ko = 0; ko < 8; ++ko) {
            bh8 wfv[4];
            #pragma unroll
            for (int ni = 0; ni < 4; ++ni)
                wfv[ni] = *(const bh8*)(w2base + (size_t)(ni * 8 + ko) * 512);
            bh8 a = *(const bh8*)&h1t[mt * 16 + lr][ko * 32 + lk * 8];
            #pragma unroll
            for (int ni = 0; ni < 4; ++ni)
                acc2[ni] = __builtin_amdgcn_mfma_f32_16x16x32_bf16(a, wfv[ni], acc2[ni], 0, 0, 0);
        }

        // C5: bias2 + residual (x1t) -> global out
        #pragma unroll
        for (int ni = 0; ni < 4; ++ni)
            #pragma unroll
            for (int r4 = 0; r4 < 4; ++r4) {
                int row32 = mt * 16 + lk * 4 + r4;
                int col = ns * 64 + ni * 16 + lr;
                float resid = bf2f(x1t[c * 32 + row32][col]);
                out[(tb + (size_t)c * 64 + row32) * DIM + col] = resid + acc2[ni][r4] + bias2v[ni];
            }
        __syncthreads();
    }
}

extern "C" void kernel_launch(void* const* d_in, const int* in_sizes, int n_in,
                              void* d_out, int out_size, void* d_ws, size_t ws_size,
                              hipStream_t stream) {
    const float* x    = (const float*)d_in[0];
    const float* g1   = (const float*)d_in[1];
    const float* b1   = (const float*)d_in[2];
    const float* btab = (const float*)d_in[3];
    const float* g2   = (const float*)d_in[6];
    const float* b2   = (const float*)d_in[7];
    const float* w1   = (const float*)d_in[8];
    const float* mb1  = (const float*)d_in[9];
    const float* w2   = (const float*)d_in[10];
    const float* mb2  = (const float*)d_in[11];
    float* out = (float*)d_out;
    unsigned short* wtf = (unsigned short*)d_ws;   // 256 KB weight area

    prep_kernel<<<64, 256, 0, stream>>>(w1, w2, wtf);
    fused_kernel<<<1024, 512, 0, stream>>>(x, g1, b1, btab, g2, b2, wtf, mb1, mb2, out);
}